// Round 3
// baseline (1604.808 us; speedup 1.0000x reference)
//
#include <hip/hip_runtime.h>
#include <hip/hip_bf16.h>
#include <cstdint>

typedef __attribute__((ext_vector_type(8))) short short8;
typedef __attribute__((ext_vector_type(4))) float float4v;

#define LOG2E 1.44269504088896340736f
#define LN2   0.69314718055994530942f

#if __has_builtin(__builtin_amdgcn_exp2f)
__device__ __forceinline__ float fexp2(float x){ return __builtin_amdgcn_exp2f(x); }
#else
__device__ __forceinline__ float fexp2(float x){ return exp2f(x); }
#endif
#if __has_builtin(__builtin_amdgcn_logf)
__device__ __forceinline__ float flog2(float x){ return __builtin_amdgcn_logf(x); }
#else
__device__ __forceinline__ float flog2(float x){ return log2f(x); }
#endif

// hhat = log2(1 + 2^zhat). With biases pre-scaled by log2e, a GEMM on hhat
// directly produces the next zhat (ln2 * log2e == 1 cancels).
__device__ __forceinline__ float softplus_hat(float zh){
  return flog2(1.0f + fexp2(zh));
}

// softplus output is strictly positive -> truncation (RTZ) to bf16 is a clean
// 1-instr shift; saves ~5 VALU/elem vs __float2bfloat16's RNE sequence.
__device__ __forceinline__ unsigned short bf16_trunc(float f){
  return (unsigned short)(__builtin_bit_cast(unsigned int, f) >> 16);
}

// ---------------------------------------------------------------------------
// Pre-pass: Wh [S,4,256,256] fp32 -> bf16 slabs Wt[s*4+l][kb][n][ki]
// (kb = k/32, ki = k%32). B-frags are read from GLOBAL: lanes {n,n+16,n+32,
// n+48} of a wave cover row n's 64B contiguously -> 1KB/wave-instr from L2.
// Weights get full RNE (cheap here, runs once over 2M elems).
// ---------------------------------------------------------------------------
__global__ void convert_wh(const float* __restrict__ Wh,
                           unsigned short* __restrict__ Wt){
  int e = blockIdx.x * 256 + threadIdx.x;          // 0 .. 2^21-1
  int n  = e & 255;
  int k  = (e >> 8) & 255;
  int sl = e >> 16;
  float v = Wh[e];
  __hip_bfloat16 h = __float2bfloat16(v);
  Wt[(sl << 16) + ((k >> 5) << 13) + (n << 5) + (k & 31)] =
      __builtin_bit_cast(unsigned short, h);
}

// ---------------------------------------------------------------------------
// Fast path: one block = 64 rows x one series, all layers fused.
// 512 threads / 8 waves; wave tile 32x64 -> acc 32 AGPR/lane, 2 blocks/CU =
// 16 waves/CU (2x round-2 occupancy) so softplus-VALU of some waves overlaps
// MFMA + L2 B-load latency of others.
// h in LDS (32KB bf16, octet^(m&7) swizzle -> conflict-free ds_read_b128).
// ---------------------------------------------------------------------------
__global__ __launch_bounds__(512, 4) void series_mlp(
    const float* __restrict__ coords,
    const float* __restrict__ W0, const float* __restrict__ b0,
    const float* __restrict__ bh,
    const float* __restrict__ Wout, const float* __restrict__ bout,
    const unsigned short* __restrict__ Wt,
    float* __restrict__ out)
{
  __shared__ __align__(16) unsigned short h_lds[64 * 256];   // 32 KB
  __shared__ float cbuf[192];
  __shared__ float red[512];

  const int tid  = threadIdx.x;
  const int lane = tid & 63;
  const int wave = tid >> 6;          // 0..7
  const int wm   = wave >> 2;         // m-half (rows wm*32 .. +32)
  const int wn   = wave & 3;          // n-quarter (cols wn*64 .. +64)
  const int s    = blockIdx.y;
  const int m0   = blockIdx.x * 64;   // 3125*64 == 200000 exactly

  if (tid < 192) cbuf[tid] = coords[m0 * 3 + tid];
  __syncthreads();

  // ---------------- layer 0: K=3, pure VALU ----------------
  {
    const int c  = tid & 255;
    const int mh = (tid >> 8) * 32;                 // each half does 32 rows
    const float w0 = W0[(s * 3 + 0) * 256 + c] * LOG2E;
    const float w1 = W0[(s * 3 + 1) * 256 + c] * LOG2E;
    const float w2 = W0[(s * 3 + 2) * 256 + c] * LOG2E;
    const float bb = b0[s * 256 + c] * LOG2E;
    const int cc = c >> 3, cl = c & 7;
    for (int m = mh; m < mh + 32; ++m) {
      float zh = fmaf(cbuf[m * 3 + 2], w2,
                 fmaf(cbuf[m * 3 + 1], w1,
                 fmaf(cbuf[m * 3 + 0], w0, bb)));
      h_lds[m * 256 + ((cc ^ (m & 7)) << 3) + cl] = bf16_trunc(softplus_hat(zh));
    }
  }
  __syncthreads();

  // ---------------- 4 hidden layers: MFMA 16x16x32 bf16 ----------------
  for (int l = 0; l < 4; ++l) {
    const unsigned short* slab = Wt + (((s << 2) + l) << 16);
    const int colb = (wn << 6) + (lane & 15);
    const int q    = lane >> 4;

    float bias[4];
    #pragma unroll
    for (int ni = 0; ni < 4; ++ni)
      bias[ni] = bh[((s << 2) + l) * 256 + colb + ni * 16] * LOG2E;

    float4v acc[2][4];
    #pragma unroll
    for (int mi = 0; mi < 2; ++mi)
      #pragma unroll
      for (int ni = 0; ni < 4; ++ni)
        acc[mi][ni] = (float4v){bias[ni], bias[ni], bias[ni], bias[ni]};

    // per-lane global base for B-frags: row n = colb + ni*16, octet q
    const unsigned short* bbase = slab + (colb << 5) + (q << 3);

    #pragma unroll
    for (int kb = 0; kb < 8; ++kb) {
      short8 af[2], bf[4];
      #pragma unroll
      for (int ni = 0; ni < 4; ++ni)
        bf[ni] = *(const short8*)(bbase + (kb << 13) + (ni << 9)); // ni*16*32
      #pragma unroll
      for (int mi = 0; mi < 2; ++mi) {
        int m = wm * 32 + mi * 16 + (lane & 15);
        int o = (kb << 2) + q;                       // octet index in row
        af[mi] = *(const short8*)&h_lds[m * 256 + ((o ^ (m & 7)) << 3)];
      }
      #pragma unroll
      for (int mi = 0; mi < 2; ++mi)
        #pragma unroll
        for (int ni = 0; ni < 4; ++ni)
          acc[mi][ni] = __builtin_amdgcn_mfma_f32_16x16x32_bf16(
              af[mi], bf[ni], acc[mi][ni], 0, 0, 0);
    }
    __syncthreads();   // all h reads (this layer) done before epilogue writes

    // epilogue: softplus_hat + truncated bf16 store back into h
    #pragma unroll
    for (int mi = 0; mi < 2; ++mi) {
      #pragma unroll
      for (int ni = 0; ni < 4; ++ni) {
        float4v v = acc[mi][ni];
        int col = (wn << 6) + ni * 16 + (lane & 15);
        int cc = col >> 3, cl = col & 7;
        int mb = wm * 32 + mi * 16 + ((lane >> 4) << 2);
        #pragma unroll
        for (int r = 0; r < 4; ++r) {
          int m = mb + r;
          h_lds[m * 256 + ((cc ^ (m & 7)) << 3) + cl] =
              bf16_trunc(softplus_hat(v[r]));
        }
      }
    }
    __syncthreads();   // h ready for next layer
  }

  // ---------------- output layer: N=1, VALU dot + block reduce ----------------
  {
    const int m  = tid & 63;
    const int q8 = tid >> 6;                         // eighth of K
    const float* wv = Wout + (s << 8);
    float sum = 0.f;
    #pragma unroll
    for (int ch = 0; ch < 4; ++ch) {
      int k = (q8 << 5) + (ch << 3);
      short8 hv = *(const short8*)&h_lds[m * 256 + (((k >> 3) ^ (m & 7)) << 3)];
      #pragma unroll
      for (int j = 0; j < 8; ++j) {
        unsigned int u = ((unsigned int)(unsigned short)hv[j]) << 16;
        sum = fmaf(__builtin_bit_cast(float, u), wv[k + j], sum);
      }
    }
    red[tid] = sum;
    __syncthreads();
    if (tid < 64) {
      float tot = 0.f;
      #pragma unroll
      for (int i = 0; i < 8; ++i) tot += red[i * 64 + tid];
      out[(m0 + tid) * 8 + s] = fmaf(LN2, tot, bout[s]);  // undo log2-domain
    }
  }
}

// ---------------------------------------------------------------------------
// Fallback (scratch-free), fp32 VALU — only if ws_size < 4 MiB.
// ---------------------------------------------------------------------------
__global__ __launch_bounds__(256) void series_mlp_slow(
    const float* __restrict__ coords,
    const float* __restrict__ W0, const float* __restrict__ b0,
    const float* __restrict__ Wh, const float* __restrict__ bh,
    const float* __restrict__ Wout, const float* __restrict__ bout,
    float* __restrict__ out)
{
  __shared__ float h[64 * 256];
  __shared__ float cbuf[192];
  __shared__ float red[256];
  const int tid = threadIdx.x;
  const int s   = blockIdx.y;
  const int m0  = blockIdx.x * 64;

  if (tid < 192) cbuf[tid] = coords[m0 * 3 + tid];
  __syncthreads();
  {
    const float w0 = W0[(s * 3 + 0) * 256 + tid];
    const float w1 = W0[(s * 3 + 1) * 256 + tid];
    const float w2 = W0[(s * 3 + 2) * 256 + tid];
    const float bb = b0[s * 256 + tid];
    for (int m = 0; m < 64; ++m) {
      float z = fmaf(cbuf[m * 3 + 2], w2,
                fmaf(cbuf[m * 3 + 1], w1,
                fmaf(cbuf[m * 3 + 0], w0, bb)));
      h[m * 256 + tid] = LN2 * softplus_hat(z * LOG2E);
    }
  }
  __syncthreads();

  for (int l = 0; l < 4; ++l) {
    const float* W = Wh + (((s << 2) + l) << 16);
    const float bb = bh[((s << 2) + l) * 256 + tid];
    float acc[64];
    #pragma unroll
    for (int m = 0; m < 64; ++m) acc[m] = bb;
    for (int kc = 0; kc < 64; ++kc) {
      float w0 = W[(kc * 4 + 0) * 256 + tid];
      float w1 = W[(kc * 4 + 1) * 256 + tid];
      float w2 = W[(kc * 4 + 2) * 256 + tid];
      float w3 = W[(kc * 4 + 3) * 256 + tid];
      #pragma unroll
      for (int m = 0; m < 64; ++m) {
        float4v hv = *(const float4v*)&h[m * 256 + kc * 4];
        acc[m] = fmaf(hv.w, w3, fmaf(hv.z, w2,
                 fmaf(hv.y, w1, fmaf(hv.x, w0, acc[m]))));
      }
    }
    __syncthreads();
    #pragma unroll
    for (int m = 0; m < 64; ++m)
      h[m * 256 + tid] = LN2 * softplus_hat(acc[m] * LOG2E);
    __syncthreads();
  }
  {
    const int m = tid >> 2, qq = tid & 3;
    const float* wv = Wout + (s << 8);
    float sum = 0.f;
    for (int i = 0; i < 16; ++i) {
      int kk = (qq << 6) + ((((tid & 15) + i) << 2) & 63);
      float4v hv = *(const float4v*)&h[m * 256 + kk];
      sum += hv.x * wv[kk] + hv.y * wv[kk + 1] + hv.z * wv[kk + 2] + hv.w * wv[kk + 3];
    }
    red[tid] = sum;
    __syncthreads();
    if (tid < 64)
      out[(m0 + tid) * 8 + s] =
          red[tid * 4] + red[tid * 4 + 1] + red[tid * 4 + 2] + red[tid * 4 + 3] + bout[s];
  }
}

extern "C" void kernel_launch(void* const* d_in, const int* in_sizes, int n_in,
                              void* d_out, int out_size, void* d_ws, size_t ws_size,
                              hipStream_t stream) {
  const float* coords = (const float*)d_in[0];
  const float* W0     = (const float*)d_in[1];
  const float* b0     = (const float*)d_in[2];
  const float* Wh     = (const float*)d_in[3];
  const float* bh     = (const float*)d_in[4];
  const float* Wout   = (const float*)d_in[5];
  const float* bout   = (const float*)d_in[6];
  float* out = (float*)d_out;

  const size_t WT_BYTES = (size_t)8 * 4 * 256 * 256 * 2;   // 4 MiB bf16 slabs
  if (ws_size >= WT_BYTES) {
    unsigned short* Wt = (unsigned short*)d_ws;
    convert_wh<<<8192, 256, 0, stream>>>(Wh, Wt);
    series_mlp<<<dim3(3125, 8), dim3(512), 0, stream>>>(
        coords, W0, b0, bh, Wout, bout, Wt, out);
  } else {
    series_mlp_slow<<<dim3(3125, 8), dim3(256), 0, stream>>>(
        coords, W0, b0, Wh, bh, Wout, bout, out);
  }
  // second tuple output: echo coords
  hipMemcpyAsync(out + (size_t)200000 * 8, coords,
                 (size_t)200000 * 3 * sizeof(float),
                 hipMemcpyDeviceToDevice, stream);
}

// Round 4
// 1246.748 us; speedup vs baseline: 1.2872x; 1.2872x over previous
//
#include <hip/hip_runtime.h>
#include <hip/hip_bf16.h>
#include <cstdint>

typedef __attribute__((ext_vector_type(8))) short short8;
typedef __attribute__((ext_vector_type(4))) float float4v;

#define LOG2E 1.44269504088896340736f
#define LN2   0.69314718055994530942f

#if __has_builtin(__builtin_amdgcn_exp2f)
__device__ __forceinline__ float fexp2(float x){ return __builtin_amdgcn_exp2f(x); }
#else
__device__ __forceinline__ float fexp2(float x){ return exp2f(x); }
#endif
#if __has_builtin(__builtin_amdgcn_logf)
__device__ __forceinline__ float flog2(float x){ return __builtin_amdgcn_logf(x); }
#else
__device__ __forceinline__ float flog2(float x){ return log2f(x); }
#endif

// hhat = log2(1 + 2^zhat). With biases pre-scaled by log2e, a GEMM on hhat
// directly produces the next zhat (ln2 * log2e == 1 cancels).
__device__ __forceinline__ float softplus_hat(float zh){
  return flog2(1.0f + fexp2(zh));
}

// softplus output > 0 -> truncation (RTZ) to bf16 is a 1-instr shift.
__device__ __forceinline__ unsigned short bf16_trunc(float f){
  return (unsigned short)(__builtin_bit_cast(unsigned int, f) >> 16);
}

// ---------------------------------------------------------------------------
// Pre-pass: Wh [S,4,256,256] fp32 -> bf16 slabs Wt[s*4+l][kb][n][ki]
// (kb = k/32, ki = k%32). B-frags are read from GLOBAL: lanes {n,n+16,n+32,
// n+48} of a wave cover row n's 64B contiguously -> 1KB/wave-instr from L2.
// ---------------------------------------------------------------------------
__global__ void convert_wh(const float* __restrict__ Wh,
                           unsigned short* __restrict__ Wt){
  int e = blockIdx.x * 256 + threadIdx.x;          // 0 .. 2^21-1
  int n  = e & 255;
  int k  = (e >> 8) & 255;
  int sl = e >> 16;
  float v = Wh[e];
  __hip_bfloat16 h = __float2bfloat16(v);
  Wt[(sl << 16) + ((k >> 5) << 13) + (n << 5) + (k & 31)] =
      __builtin_bit_cast(unsigned short, h);
}

// ---------------------------------------------------------------------------
// Fused MLP. Round-2 shape (4 waves, wave tile 64m x 64n, ~96-120 VGPR) with:
//  * softplus applied to acc IN REGS before the barrier (straggler MFMA
//    overlaps finished waves' transcendentals)
//  * output layer fused into layer-3 epilogue (no h4 write-back / re-read)
//  * single 32KB h buffer -> ~34KB LDS -> up to 4 blocks/CU
// ---------------------------------------------------------------------------
__global__ __launch_bounds__(256, 2) void series_mlp(
    const float* __restrict__ coords,
    const float* __restrict__ W0, const float* __restrict__ b0,
    const float* __restrict__ bh,
    const float* __restrict__ Wout, const float* __restrict__ bout,
    const unsigned short* __restrict__ Wt,
    float* __restrict__ out)
{
  __shared__ __align__(16) unsigned short h_lds[64 * 256];   // 32 KB
  __shared__ float cbuf[192];

  const int tid  = threadIdx.x;
  const int lane = tid & 63;
  const int wave = tid >> 6;          // wave owns cols [wave*64, +64), all 64 rows
  const int s    = blockIdx.y;
  const int m0   = blockIdx.x * 64;   // 3125*64 == 200000 exactly

  if (tid < 192) cbuf[tid] = coords[m0 * 3 + tid];
  __syncthreads();

  // ---------------- layer 0: K=3, pure VALU ----------------
  {
    const int c  = tid;
    const float w0 = W0[(s * 3 + 0) * 256 + c] * LOG2E;
    const float w1 = W0[(s * 3 + 1) * 256 + c] * LOG2E;
    const float w2 = W0[(s * 3 + 2) * 256 + c] * LOG2E;
    const float bb = b0[s * 256 + c] * LOG2E;
    const int cc = c >> 3, cl = c & 7;
    for (int m = 0; m < 64; ++m) {
      float zh = fmaf(cbuf[m * 3 + 2], w2,
                 fmaf(cbuf[m * 3 + 1], w1,
                 fmaf(cbuf[m * 3 + 0], w0, bb)));
      h_lds[m * 256 + ((cc ^ (m & 7)) << 3) + cl] = bf16_trunc(softplus_hat(zh));
    }
  }
  __syncthreads();

  const int colb = (wave << 6) + (lane & 15);
  const int q    = lane >> 4;

  // ---------------- hidden layers 0..2: MFMA 16x16x32 bf16 ----------------
  for (int l = 0; l < 3; ++l) {
    const unsigned short* slab = Wt + (((s << 2) + l) << 16);

    float bias[4];
    #pragma unroll
    for (int ni = 0; ni < 4; ++ni)
      bias[ni] = bh[((s << 2) + l) * 256 + colb + ni * 16] * LOG2E;

    float4v acc[4][4];
    #pragma unroll
    for (int mi = 0; mi < 4; ++mi)
      #pragma unroll
      for (int ni = 0; ni < 4; ++ni)
        acc[mi][ni] = (float4v){bias[ni], bias[ni], bias[ni], bias[ni]};

    const unsigned short* bbase = slab + (colb << 5) + (q << 3);

    #pragma unroll
    for (int kb = 0; kb < 8; ++kb) {
      short8 af[4], bf[4];
      #pragma unroll
      for (int ni = 0; ni < 4; ++ni)
        bf[ni] = *(const short8*)(bbase + (kb << 13) + (ni << 9));
      #pragma unroll
      for (int mi = 0; mi < 4; ++mi) {
        int m = mi * 16 + (lane & 15);
        int o = (kb << 2) + q;
        af[mi] = *(const short8*)&h_lds[m * 256 + ((o ^ (m & 7)) << 3)];
      }
      #pragma unroll
      for (int mi = 0; mi < 4; ++mi)
        #pragma unroll
        for (int ni = 0; ni < 4; ++ni)
          acc[mi][ni] = __builtin_amdgcn_mfma_f32_16x16x32_bf16(
              af[mi], bf[ni], acc[mi][ni], 0, 0, 0);
    }

    // softplus in regs BEFORE the barrier (overlaps other waves' MFMA tail)
    #pragma unroll
    for (int mi = 0; mi < 4; ++mi)
      #pragma unroll
      for (int ni = 0; ni < 4; ++ni) {
        float4v v = acc[mi][ni];
        #pragma unroll
        for (int r = 0; r < 4; ++r) v[r] = softplus_hat(v[r]);
        acc[mi][ni] = v;
      }

    __syncthreads();   // all A-reads of h done -> safe to overwrite

    #pragma unroll
    for (int mi = 0; mi < 4; ++mi) {
      #pragma unroll
      for (int ni = 0; ni < 4; ++ni) {
        float4v v = acc[mi][ni];
        int col = (wave << 6) + ni * 16 + (lane & 15);
        int cc = col >> 3, cl = col & 7;
        int mb = mi * 16 + (q << 2);
        #pragma unroll
        for (int r = 0; r < 4; ++r) {
          int m = mb + r;
          h_lds[m * 256 + ((cc ^ (m & 7)) << 3) + cl] = bf16_trunc(v[r]);
        }
      }
    }
    __syncthreads();   // h ready for next layer
  }

  // ------- layer 3: MFMA + fused output (dot with Wout, no h write-back) -------
  {
    const unsigned short* slab = Wt + (((s << 2) + 3) << 16);

    float bias[4];
    #pragma unroll
    for (int ni = 0; ni < 4; ++ni)
      bias[ni] = bh[((s << 2) + 3) * 256 + colb + ni * 16] * LOG2E;

    float4v acc[4][4];
    #pragma unroll
    for (int mi = 0; mi < 4; ++mi)
      #pragma unroll
      for (int ni = 0; ni < 4; ++ni)
        acc[mi][ni] = (float4v){bias[ni], bias[ni], bias[ni], bias[ni]};

    const unsigned short* bbase = slab + (colb << 5) + (q << 3);

    #pragma unroll
    for (int kb = 0; kb < 8; ++kb) {
      short8 af[4], bf[4];
      #pragma unroll
      for (int ni = 0; ni < 4; ++ni)
        bf[ni] = *(const short8*)(bbase + (kb << 13) + (ni << 9));
      #pragma unroll
      for (int mi = 0; mi < 4; ++mi) {
        int m = mi * 16 + (lane & 15);
        int o = (kb << 2) + q;
        af[mi] = *(const short8*)&h_lds[m * 256 + ((o ^ (m & 7)) << 3)];
      }
      #pragma unroll
      for (int mi = 0; mi < 4; ++mi)
        #pragma unroll
        for (int ni = 0; ni < 4; ++ni)
          acc[mi][ni] = __builtin_amdgcn_mfma_f32_16x16x32_bf16(
              af[mi], bf[ni], acc[mi][ni], 0, 0, 0);
    }

    // softplus + per-lane partial dot over this wave's 4 cols (fp32 h4 -> more
    // accurate than the old bf16 round-trip). Pre-barrier VALU.
    float wv[4];
    #pragma unroll
    for (int ni = 0; ni < 4; ++ni)
      wv[ni] = Wout[(s << 8) + colb + ni * 16];
    float p[16];
    #pragma unroll
    for (int i = 0; i < 16; ++i) p[i] = 0.f;
    #pragma unroll
    for (int mi = 0; mi < 4; ++mi)
      #pragma unroll
      for (int ni = 0; ni < 4; ++ni) {
        float4v v = acc[mi][ni];
        #pragma unroll
        for (int r = 0; r < 4; ++r)
          p[mi * 4 + r] = fmaf(softplus_hat(v[r]), wv[ni], p[mi * 4 + r]);
      }

    __syncthreads();                    // all A-reads done; h_lds reusable
    float* red = (float*)h_lds;         // 64 rows x 64 partials, stride 68 pad
    #pragma unroll
    for (int mi = 0; mi < 4; ++mi)
      #pragma unroll
      for (int r = 0; r < 4; ++r) {
        int row = mi * 16 + (q << 2) + r;
        red[row * 68 + (wave << 4) + (lane & 15)] = p[mi * 4 + r];
      }
    __syncthreads();

    if (tid < 64) {
      const float4v* rr = (const float4v*)&red[tid * 68];
      float4v a = rr[0];
      #pragma unroll
      for (int i = 1; i < 16; ++i) {
        float4v b = rr[i];
        a.x += b.x; a.y += b.y; a.z += b.z; a.w += b.w;
      }
      float tot = (a.x + a.y) + (a.z + a.w);
      out[(m0 + tid) * 8 + s] = fmaf(LN2, tot, bout[s]);  // undo log2-domain
    }
  }
}

// ---------------------------------------------------------------------------
// Fallback (scratch-free), fp32 VALU — only if ws_size < 4 MiB.
// ---------------------------------------------------------------------------
__global__ __launch_bounds__(256) void series_mlp_slow(
    const float* __restrict__ coords,
    const float* __restrict__ W0, const float* __restrict__ b0,
    const float* __restrict__ Wh, const float* __restrict__ bh,
    const float* __restrict__ Wout, const float* __restrict__ bout,
    float* __restrict__ out)
{
  __shared__ float h[64 * 256];
  __shared__ float cbuf[192];
  __shared__ float red[256];
  const int tid = threadIdx.x;
  const int s   = blockIdx.y;
  const int m0  = blockIdx.x * 64;

  if (tid < 192) cbuf[tid] = coords[m0 * 3 + tid];
  __syncthreads();
  {
    const float w0 = W0[(s * 3 + 0) * 256 + tid];
    const float w1 = W0[(s * 3 + 1) * 256 + tid];
    const float w2 = W0[(s * 3 + 2) * 256 + tid];
    const float bb = b0[s * 256 + tid];
    for (int m = 0; m < 64; ++m) {
      float z = fmaf(cbuf[m * 3 + 2], w2,
                fmaf(cbuf[m * 3 + 1], w1,
                fmaf(cbuf[m * 3 + 0], w0, bb)));
      h[m * 256 + tid] = LN2 * softplus_hat(z * LOG2E);
    }
  }
  __syncthreads();

  for (int l = 0; l < 4; ++l) {
    const float* W = Wh + (((s << 2) + l) << 16);
    const float bb = bh[((s << 2) + l) * 256 + tid];
    float acc[64];
    #pragma unroll
    for (int m = 0; m < 64; ++m) acc[m] = bb;
    for (int kc = 0; kc < 64; ++kc) {
      float w0 = W[(kc * 4 + 0) * 256 + tid];
      float w1 = W[(kc * 4 + 1) * 256 + tid];
      float w2 = W[(kc * 4 + 2) * 256 + tid];
      float w3 = W[(kc * 4 + 3) * 256 + tid];
      #pragma unroll
      for (int m = 0; m < 64; ++m) {
        float4v hv = *(const float4v*)&h[m * 256 + kc * 4];
        acc[m] = fmaf(hv.w, w3, fmaf(hv.z, w2,
                 fmaf(hv.y, w1, fmaf(hv.x, w0, acc[m]))));
      }
    }
    __syncthreads();
    #pragma unroll
    for (int m = 0; m < 64; ++m)
      h[m * 256 + tid] = LN2 * softplus_hat(acc[m] * LOG2E);
    __syncthreads();
  }
  {
    const int m = tid >> 2, qq = tid & 3;
    const float* wv = Wout + (s << 8);
    float sum = 0.f;
    for (int i = 0; i < 16; ++i) {
      int kk = (qq << 6) + ((((tid & 15) + i) << 2) & 63);
      float4v hv = *(const float4v*)&h[m * 256 + kk];
      sum += hv.x * wv[kk] + hv.y * wv[kk + 1] + hv.z * wv[kk + 2] + hv.w * wv[kk + 3];
    }
    red[tid] = sum;
    __syncthreads();
    if (tid < 64)
      out[(m0 + tid) * 8 + s] =
          red[tid * 4] + red[tid * 4 + 1] + red[tid * 4 + 2] + red[tid * 4 + 3] + bout[s];
  }
}

extern "C" void kernel_launch(void* const* d_in, const int* in_sizes, int n_in,
                              void* d_out, int out_size, void* d_ws, size_t ws_size,
                              hipStream_t stream) {
  const float* coords = (const float*)d_in[0];
  const float* W0     = (const float*)d_in[1];
  const float* b0     = (const float*)d_in[2];
  const float* Wh     = (const float*)d_in[3];
  const float* bh     = (const float*)d_in[4];
  const float* Wout   = (const float*)d_in[5];
  const float* bout   = (const float*)d_in[6];
  float* out = (float*)d_out;

  const size_t WT_BYTES = (size_t)8 * 4 * 256 * 256 * 2;   // 4 MiB bf16 slabs
  if (ws_size >= WT_BYTES) {
    unsigned short* Wt = (unsigned short*)d_ws;
    convert_wh<<<8192, 256, 0, stream>>>(Wh, Wt);
    series_mlp<<<dim3(3125, 8), dim3(256), 0, stream>>>(
        coords, W0, b0, bh, Wout, bout, Wt, out);
  } else {
    series_mlp_slow<<<dim3(3125, 8), dim3(256), 0, stream>>>(
        coords, W0, b0, Wh, bh, Wout, bout, out);
  }
  // second tuple output: echo coords
  hipMemcpyAsync(out + (size_t)200000 * 8, coords,
                 (size_t)200000 * 3 * sizeof(float),
                 hipMemcpyDeviceToDevice, stream);
}